// Round 19
// baseline (88.132 us; speedup 1.0000x reference)
//
#include <hip/hip_runtime.h>
#include <hip/hip_bf16.h>
#include <hip/hip_fp8.h>

typedef float f32x4 __attribute__((ext_vector_type(4)));
typedef int i32x4 __attribute__((ext_vector_type(4)));
typedef int i32x8 __attribute__((ext_vector_type(8)));

typedef __attribute__((address_space(3))) void as3_void;
typedef const __attribute__((address_space(1))) void as1_void;

static constexpr int D = 256;
static constexpr float INV_T = 10.0f;  // 1 / 0.1

__device__ __forceinline__ unsigned char f2fp8(float x) {
  __hip_fp8_e4m3 q(x);               // OCP e4m3fn (gfx950)
  return (unsigned char)q.__x;
}

// Kernel 1: L2-normalize rows -> fp8 e4m3; diag logits exact in fp32.
__global__ __launch_bounds__(256) void normalize_kernel(
    const float* __restrict__ im, const float* __restrict__ cap,
    unsigned char* __restrict__ imn, unsigned char* __restrict__ capn,
    float* __restrict__ diag, int N) {
  int tid = blockIdx.x * 256 + threadIdx.x;
  int w = tid >> 6;
  int lane = threadIdx.x & 63;
  if (w >= N) return;
  float4 vi = ((const float4*)(im + (size_t)w * D))[lane];
  float4 vc = ((const float4*)(cap + (size_t)w * D))[lane];
  float ssi = vi.x*vi.x + vi.y*vi.y + vi.z*vi.z + vi.w*vi.w;
  float ssc = vc.x*vc.x + vc.y*vc.y + vc.z*vc.z + vc.w*vc.w;
  #pragma unroll
  for (int m = 1; m < 64; m <<= 1) {
    ssi += __shfl_xor(ssi, m);
    ssc += __shfl_xor(ssc, m);
  }
  float ri = 1.0f / fmaxf(sqrtf(ssi), 1e-12f);
  float rc = 1.0f / fmaxf(sqrtf(ssc), 1e-12f);
  float ax = vi.x*ri, ay = vi.y*ri, az = vi.z*ri, aw = vi.w*ri;
  float cx = vc.x*rc, cy = vc.y*rc, cz = vc.z*rc, cw = vc.w*rc;
  uchar4 ua, uc;
  ua.x = f2fp8(ax); ua.y = f2fp8(ay); ua.z = f2fp8(az); ua.w = f2fp8(aw);
  uc.x = f2fp8(cx); uc.y = f2fp8(cy); uc.z = f2fp8(cz); uc.w = f2fp8(cw);
  ((uchar4*)(imn + (size_t)w * D))[lane] = ua;
  ((uchar4*)(capn + (size_t)w * D))[lane] = uc;
  float d = ax*cx + ay*cy + az*cz + aw*cw;
  #pragma unroll
  for (int m = 1; m < 64; m <<= 1) d += __shfl_xor(d, m);
  if (lane == 0) diag[w] = d * INV_T;
}

// Kernel 2: MX-fp8 GEMM (mfma_scale 16x16x128, scales = 1.0). r18 shell with
// two fixes:
//  (1) SPILL FIX: COMPUTE is ni-outer/mi-inner with ONE live B-frag and one
//      transient A-frag (r18 held 5 i32x8 frags live -> 14MB scratch spill
//      at the 128-VGPR cap; acc lives in AGPRs of the unified file).
//  (2) SWIZZLE FIX: stored 16B-unit u = u' ^ ((row>>1)+(row>>3)+sub)&3 --
//      the +sub term separates kp-quarter pairs that r18 mapped to the same
//      banks (1.57M conflicts).
// Shell: grid 256 (1/CU), block = bm(256 rows) x 4 bn-tiles(256 cols); 8
// waves 2Mx4N; A resident [sub4][row256][64B] = 64KB; B per-K-half
// [sub2][col256][64B] = 32KB x 2 buffers; LDS 128KB. 8 compute steps of
// 32 K=128-MFMAs; stage-ahead 2 half-steps; counted vmcnt(4).
__global__ __launch_bounds__(512) void gemm_exp_kernel(
    const unsigned char* __restrict__ A, const unsigned char* __restrict__ Bm,
    float* __restrict__ rowpart, float* __restrict__ colpart, int N) {
  __shared__ unsigned char AsF[65536];      // [sub4][row 256][64B]
  __shared__ unsigned char BsF[2][32768];   // [sub2][col 256][64B] each
  int bm = blockIdx.x >> 3;
  int grp = blockIdx.x & 7;
  int tid = threadIdx.x;
  int lane = tid & 63;
  int wv = tid >> 6;
  int wm = wv >> 2;            // rows [wm*128, +128)
  int wn = wv & 3;             // cols [wn*64, +64)
  int rb = lane & 15;
  int kp = lane >> 4;          // k-part 0..3 (32B each)

  f32x4 acc[8][4];

  // staging source offsets: slot s covers 16B unit; sub = s>>10,
  // row = (s>>2)&255, u' = s&3, stored u = u' ^ ((row>>1)+(row>>3)+sub)&3.
  int sb = wv * 64 + lane;
  int boff[4];
  #pragma unroll
  for (int q = 0; q < 4; ++q) {
    int s = q * 512 + sb;
    int sub = s >> 10, row = (s >> 2) & 255;
    int u = (s & 3) ^ (((row >> 1) + (row >> 3) + sub) & 3);
    boff[q] = row * 256 + sub * 64 + u * 16;
  }

#define VMWAIT(n) asm volatile("s_waitcnt vmcnt(" #n ")" ::: "memory")
#define LGKM0() asm volatile("s_waitcnt lgkmcnt(0)" ::: "memory")
#define BARRIER() asm volatile("s_barrier" ::: "memory")

#define STAGE_B(P, TILE, KH) {                                               \
    const unsigned char* bsrc_ = Bm + (size_t)(TILE) * 65536 + (KH) * 128;   \
    _Pragma("unroll")                                                        \
    for (int q = 0; q < 4; ++q)                                              \
      __builtin_amdgcn_global_load_lds((as1_void*)(bsrc_ + boff[q]),         \
          (as3_void*)(&BsF[P][q * 8192 + wv * 1024]), 16, 0, 0);             \
  }

#define READ_A8(dst, mi, KH) {                                               \
    int row_ = wm * 128 + (mi) * 16 + rb;                                    \
    int sub_ = (KH) * 2 + (kp >> 1);                                         \
    int h3_ = ((row_ >> 1) + (row_ >> 3) + sub_) & 3;                        \
    const unsigned char* ab_ = &AsF[sub_ * 16384 + row_ * 64];               \
    i32x4 lo_ = *(const i32x4*)(ab_ + ((((kp & 1) * 2 + 0) ^ h3_) << 4));    \
    i32x4 hi_ = *(const i32x4*)(ab_ + ((((kp & 1) * 2 + 1) ^ h3_) << 4));    \
    dst = __builtin_shufflevector(lo_, hi_, 0, 1, 2, 3, 4, 5, 6, 7);         \
  }

#define READ_B8(dst, ni, P) {                                                \
    int col_ = wn * 64 + (ni) * 16 + rb;                                     \
    int sub_ = kp >> 1;                                                      \
    int h3_ = ((col_ >> 1) + (col_ >> 3) + sub_) & 3;                        \
    const unsigned char* bb_ = &BsF[P][sub_ * 16384 + col_ * 64];            \
    i32x4 lo_ = *(const i32x4*)(bb_ + ((((kp & 1) * 2 + 0) ^ h3_) << 4));    \
    i32x4 hi_ = *(const i32x4*)(bb_ + ((((kp & 1) * 2 + 1) ^ h3_) << 4));    \
    dst = __builtin_shufflevector(lo_, hi_, 0, 1, 2, 3, 4, 5, 6, 7);         \
  }

  // one K-half compute, ni-outer/mi-inner: 1 live B-frag + 1 transient
  // A-frag (minimal register liveness -- no spill at the 128 cap).
#define COMPUTE(P, KH, CZ) {                                                 \
    _Pragma("unroll")                                                        \
    for (int ni = 0; ni < 4; ++ni) {                                         \
      i32x8 b8;                                                              \
      READ_B8(b8, ni, P)                                                     \
      __builtin_amdgcn_s_setprio(1);                                         \
      _Pragma("unroll")                                                      \
      for (int mi = 0; mi < 8; ++mi) {                                       \
        i32x8 a8;                                                            \
        READ_A8(a8, mi, KH)                                                  \
        acc[mi][ni] = __builtin_amdgcn_mfma_scale_f32_16x16x128_f8f6f4(      \
            a8, b8,                                                          \
            (CZ) ? (f32x4){0.f, 0.f, 0.f, 0.f} : acc[mi][ni],                \
            0, 0, 0, 0x7F7F7F7F, 0, 0x7F7F7F7F);                             \
      }                                                                      \
      __builtin_amdgcn_s_setprio(0);                                         \
    }                                                                        \
    LGKM0();                                                                 \
  }

  // r13-verified epilogue (16x16 C/D layout; packed 4-value butterfly)
#define EPILOGUE(BN) {                                                        \
    _Pragma("unroll")                                                         \
    for (int mi = 0; mi < 8; ++mi)                                            \
      _Pragma("unroll")                                                       \
      for (int ni = 0; ni < 4; ++ni)                                          \
        _Pragma("unroll")                                                     \
        for (int r = 0; r < 4; ++r)                                           \
          acc[mi][ni][r] = __expf(acc[mi][ni][r] * INV_T);                    \
    bool sb0 = (lane & 1) != 0, sb1 = (lane & 2) != 0;                        \
    _Pragma("unroll")                                                         \
    for (int mi = 0; mi < 8; ++mi) {                                          \
      float v0 = acc[mi][0][0] + acc[mi][1][0] + acc[mi][2][0] + acc[mi][3][0]; \
      float v1 = acc[mi][0][1] + acc[mi][1][1] + acc[mi][2][1] + acc[mi][3][1]; \
      float v2 = acc[mi][0][2] + acc[mi][1][2] + acc[mi][2][2] + acc[mi][3][2]; \
      float v3 = acc[mi][0][3] + acc[mi][1][3] + acc[mi][2][3] + acc[mi][3][3]; \
      float h0 = (sb0 ? v1 : v0) + __shfl_xor(sb0 ? v0 : v1, 1);              \
      float h1 = (sb0 ? v3 : v2) + __shfl_xor(sb0 ? v2 : v3, 1);              \
      float g  = (sb1 ? h1 : h0) + __shfl_xor(sb1 ? h0 : h1, 2);              \
      g += __shfl_xor(g, 4);                                                  \
      g += __shfl_xor(g, 8);                                                  \
      if ((lane & 12) == 0)                                                   \
        rowpart[(size_t)((BN) * 4 + wn) * N + bm * 256 + wm * 128 + mi * 16 + \
                (lane >> 4) * 4 + (lane & 3)] = g;                            \
    }                                                                         \
    _Pragma("unroll")                                                         \
    for (int ni = 0; ni < 4; ++ni) {                                          \
      float v = 0.f;                                                          \
      _Pragma("unroll")                                                       \
      for (int mi = 0; mi < 8; ++mi)                                          \
        _Pragma("unroll")                                                     \
        for (int r = 0; r < 4; ++r)                                           \
          v += acc[mi][ni][r];                                                \
      v += __shfl_xor(v, 16); v += __shfl_xor(v, 32);                         \
      if (lane < 16)                                                          \
        colpart[(size_t)(bm * 2 + wm) * N + (BN) * 256 + wn * 64 + ni * 16 +  \
                lane] = v;                                                    \
    }                                                                         \
  }

#define TILE(j) (grp * 4 + (j))

  // ---- Prologue: A (8 loads/thread) + B(tile0, half0, half1)
  #pragma unroll
  for (int q = 0; q < 8; ++q) {
    int s = q * 512 + sb;
    int sub = s >> 10, row = (s >> 2) & 255;
    int u = (s & 3) ^ (((row >> 1) + (row >> 3) + sub) & 3);
    __builtin_amdgcn_global_load_lds(
        (as1_void*)(A + (size_t)bm * 65536 + row * 256 + sub * 64 + u * 16),
        (as3_void*)(&AsF[q * 8192 + wv * 1024]), 16, 0, 0);
  }
  STAGE_B(0, TILE(0), 0)
  STAGE_B(1, TILE(0), 1)
  VMWAIT(4); BARRIER();   // A + half0 resident; half1 (newest 4) in flight

  // 8 half-steps; stage half i+2 into buf i&1 after the barrier frees it.
  COMPUTE(0, 0, 1) BARRIER();               STAGE_B(0, TILE(1), 0) VMWAIT(4); BARRIER();
  COMPUTE(1, 1, 0) BARRIER(); EPILOGUE(TILE(0)) STAGE_B(1, TILE(1), 1) VMWAIT(4); BARRIER();
  COMPUTE(0, 0, 1) BARRIER();               STAGE_B(0, TILE(2), 0) VMWAIT(4); BARRIER();
  COMPUTE(1, 1, 0) BARRIER(); EPILOGUE(TILE(1)) STAGE_B(1, TILE(2), 1) VMWAIT(4); BARRIER();
  COMPUTE(0, 0, 1) BARRIER();               STAGE_B(0, TILE(3), 0) VMWAIT(4); BARRIER();
  COMPUTE(1, 1, 0) BARRIER(); EPILOGUE(TILE(2)) STAGE_B(1, TILE(3), 1) VMWAIT(4); BARRIER();
  COMPUTE(0, 0, 1) BARRIER();               VMWAIT(0); BARRIER();
  COMPUTE(1, 1, 0) EPILOGUE(TILE(3))
  VMWAIT(0);  // retire final stores

#undef TILE
#undef EPILOGUE
#undef COMPUTE
#undef READ_B8
#undef READ_A8
#undef STAGE_B
#undef VMWAIT
#undef LGKM0
#undef BARRIER
}

// Kernel 3: partial reduction + per-sample loss + atomic accumulate into out.
__global__ __launch_bounds__(256) void reduce_kernel(
    const float* __restrict__ rowpart, const float* __restrict__ colpart,
    const float* __restrict__ diag, float* __restrict__ out,
    int N, int NPr, int NPc) {
  __shared__ float redr[4][64], redc[4][64];
  int w = threadIdx.x >> 6, s = threadIdx.x & 63;
  int i = blockIdx.x * 64 + s;
  float rs = 0.f, cs = 0.f;
  for (int k = w; k < NPr; k += 4) rs += rowpart[(size_t)k * N + i];
  for (int k = w; k < NPc; k += 4) cs += colpart[(size_t)k * N + i];
  redr[w][s] = rs; redc[w][s] = cs;
  __syncthreads();
  if (w == 0) {
    float R = redr[0][s] + redr[1][s] + redr[2][s] + redr[3][s];
    float C = redc[0][s] + redc[1][s] + redc[2][s] + redc[3][s];
    float l = logf(R) + logf(C) - 2.0f * diag[i];
    #pragma unroll
    for (int m = 1; m < 64; m <<= 1) l += __shfl_xor(l, m);
    if (s == 0) atomicAdd(out, l * (0.5f / (float)N));
  }
}

extern "C" void kernel_launch(void* const* d_in, const int* in_sizes, int n_in,
                              void* d_out, int out_size, void* d_ws, size_t ws_size,
                              hipStream_t stream) {
  const float* images = (const float*)d_in[0];
  const float* captions = (const float*)d_in[1];
  int N = in_sizes[0] / D;   // 8192
  int NPr = 128;             // 32 bn-tiles x 4 wn
  int NPc = 64;              // 32 bm-blocks x 2 wm
  char* w = (char*)d_ws;
  size_t off = 0;
  unsigned char* imn  = (unsigned char*)(w + off); off += (size_t)N * D;
  unsigned char* capn = (unsigned char*)(w + off); off += (size_t)N * D;
  float* diag    = (float*)(w + off); off += (size_t)N * 4;
  float* rowpart = (float*)(w + off); off += (size_t)NPr * N * 4;
  float* colpart = (float*)(w + off); off += (size_t)NPc * N * 4;
  float* out = (float*)d_out;

  normalize_kernel<<<N / 4, 256, 0, stream>>>(images, captions, imn, capn, diag, N);
  gemm_exp_kernel<<<256, 512, 0, stream>>>(imn, capn, rowpart, colpart, N);
  hipMemsetAsync(out, 0, sizeof(float), stream);
  reduce_kernel<<<N / 64, 256, 0, stream>>>(rowpart, colpart, diag, out, N, NPr, NPc);
}

// Round 20
// 63.668 us; speedup vs baseline: 1.3842x; 1.3842x over previous
//
#include <hip/hip_runtime.h>
#include <hip/hip_bf16.h>
#include <hip/hip_fp8.h>

typedef float f32x4 __attribute__((ext_vector_type(4)));
typedef int i32x4 __attribute__((ext_vector_type(4)));
typedef int i32x8 __attribute__((ext_vector_type(8)));

typedef __attribute__((address_space(3))) void as3_void;
typedef const __attribute__((address_space(1))) void as1_void;

static constexpr int D = 256;
static constexpr float INV_T = 10.0f;  // 1 / 0.1

__device__ __forceinline__ unsigned char f2fp8(float x) {
  __hip_fp8_e4m3 q(x);               // OCP e4m3fn (gfx950)
  return (unsigned char)q.__x;
}

// Kernel 1: L2-normalize rows -> fp8 e4m3; diag logits exact in fp32.
__global__ __launch_bounds__(256) void normalize_kernel(
    const float* __restrict__ im, const float* __restrict__ cap,
    unsigned char* __restrict__ imn, unsigned char* __restrict__ capn,
    float* __restrict__ diag, int N) {
  int tid = blockIdx.x * 256 + threadIdx.x;
  int w = tid >> 6;
  int lane = threadIdx.x & 63;
  if (w >= N) return;
  float4 vi = ((const float4*)(im + (size_t)w * D))[lane];
  float4 vc = ((const float4*)(cap + (size_t)w * D))[lane];
  float ssi = vi.x*vi.x + vi.y*vi.y + vi.z*vi.z + vi.w*vi.w;
  float ssc = vc.x*vc.x + vc.y*vc.y + vc.z*vc.z + vc.w*vc.w;
  #pragma unroll
  for (int m = 1; m < 64; m <<= 1) {
    ssi += __shfl_xor(ssi, m);
    ssc += __shfl_xor(ssc, m);
  }
  float ri = 1.0f / fmaxf(sqrtf(ssi), 1e-12f);
  float rc = 1.0f / fmaxf(sqrtf(ssc), 1e-12f);
  float ax = vi.x*ri, ay = vi.y*ri, az = vi.z*ri, aw = vi.w*ri;
  float cx = vc.x*rc, cy = vc.y*rc, cz = vc.z*rc, cw = vc.w*rc;
  uchar4 ua, uc;
  ua.x = f2fp8(ax); ua.y = f2fp8(ay); ua.z = f2fp8(az); ua.w = f2fp8(aw);
  uc.x = f2fp8(cx); uc.y = f2fp8(cy); uc.z = f2fp8(cz); uc.w = f2fp8(cw);
  ((uchar4*)(imn + (size_t)w * D))[lane] = ua;
  ((uchar4*)(capn + (size_t)w * D))[lane] = uc;
  float d = ax*cx + ay*cy + az*cz + aw*cw;
  #pragma unroll
  for (int m = 1; m < 64; m <<= 1) d += __shfl_xor(d, m);
  if (lane == 0) diag[w] = d * INV_T;
}

// Kernel 2: MX-fp8 GEMM (mfma_scale 16x16x128, scales = 1.0). r18 shell
// (best measured: 45.5us) with ONE change: COMPUTE is an explicit 1-deep
// A-frag software pipeline with sched_barrier(0) liveness pins.
//  - read of A-frag (mi+1) issued BEFORE the MFMA quartet of mi -> the read
//    completes under the ~140cy quartet: zero exposed latency;
//  - sched_barrier(0) after each quartet stops the scheduler from hoisting
//    read (mi+2) -> bounded liveness: 4 B-frags + 2 A-frags (~70 VGPR),
//    no spill at the 128 cap (r19's unpinned version spilled 88MB).
// Swizzle r18-verbatim (stored u = u' ^ ((row>>1)+(row>>3))&3, both sides).
__global__ __launch_bounds__(512) void gemm_exp_kernel(
    const unsigned char* __restrict__ A, const unsigned char* __restrict__ Bm,
    float* __restrict__ rowpart, float* __restrict__ colpart, int N) {
  __shared__ unsigned char AsF[65536];      // [sub4][row 256][64B]
  __shared__ unsigned char BsF[2][32768];   // [sub2][col 256][64B] each
  int bm = blockIdx.x >> 3;
  int grp = blockIdx.x & 7;
  int tid = threadIdx.x;
  int lane = tid & 63;
  int wv = tid >> 6;
  int wm = wv >> 2;            // rows [wm*128, +128)
  int wn = wv & 3;             // cols [wn*64, +64)
  int rb = lane & 15;
  int kp = lane >> 4;          // k-part 0..3 (32B each)

  f32x4 acc[8][4];

  // staging source offsets (r18): slot s covers 16B unit; sub = s>>10,
  // row = (s>>2)&255, u' = s&3, stored u = u' ^ ((row>>1)+(row>>3))&3.
  int sb = wv * 64 + lane;
  int boff[4];
  #pragma unroll
  for (int q = 0; q < 4; ++q) {
    int s = q * 512 + sb;
    int sub = s >> 10, row = (s >> 2) & 255;
    int u = (s & 3) ^ (((row >> 1) + (row >> 3)) & 3);
    boff[q] = row * 256 + sub * 64 + u * 16;
  }

#define VMWAIT(n) asm volatile("s_waitcnt vmcnt(" #n ")" ::: "memory")
#define LGKM0() asm volatile("s_waitcnt lgkmcnt(0)" ::: "memory")
#define BARRIER() asm volatile("s_barrier" ::: "memory")

#define STAGE_B(P, TILE, KH) {                                               \
    const unsigned char* bsrc_ = Bm + (size_t)(TILE) * 65536 + (KH) * 128;   \
    _Pragma("unroll")                                                        \
    for (int q = 0; q < 4; ++q)                                              \
      __builtin_amdgcn_global_load_lds((as1_void*)(bsrc_ + boff[q]),         \
          (as3_void*)(&BsF[P][q * 8192 + wv * 1024]), 16, 0, 0);             \
  }

#define READ_A8(dst, mi, KH) {                                               \
    int row_ = wm * 128 + (mi) * 16 + rb;                                    \
    int h2_ = ((row_ >> 1) + (row_ >> 3)) & 3;                               \
    const unsigned char* ab_ =                                               \
        &AsF[((KH) * 2 + (kp >> 1)) * 16384 + row_ * 64];                    \
    i32x4 lo_ = *(const i32x4*)(ab_ + ((((kp & 1) * 2 + 0) ^ h2_) << 4));    \
    i32x4 hi_ = *(const i32x4*)(ab_ + ((((kp & 1) * 2 + 1) ^ h2_) << 4));    \
    dst = __builtin_shufflevector(lo_, hi_, 0, 1, 2, 3, 4, 5, 6, 7);         \
  }

#define READ_B8(dst, ni, P) {                                                \
    int col_ = wn * 64 + (ni) * 16 + rb;                                     \
    int h2_ = ((col_ >> 1) + (col_ >> 3)) & 3;                               \
    const unsigned char* bb_ = &BsF[P][(kp >> 1) * 16384 + col_ * 64];       \
    i32x4 lo_ = *(const i32x4*)(bb_ + ((((kp & 1) * 2 + 0) ^ h2_) << 4));    \
    i32x4 hi_ = *(const i32x4*)(bb_ + ((((kp & 1) * 2 + 1) ^ h2_) << 4));    \
    dst = __builtin_shufflevector(lo_, hi_, 0, 1, 2, 3, 4, 5, 6, 7);         \
  }

  // MFMA quartet for row-frag AF against the 4 held B-frags, then a
  // liveness pin (no later reads may hoist above this point).
#define MFMA4(AF, MI, CZ)                                                    \
  __builtin_amdgcn_s_setprio(1);                                             \
  acc[MI][0] = __builtin_amdgcn_mfma_scale_f32_16x16x128_f8f6f4(             \
      AF, b0_, (CZ) ? (f32x4){0.f,0.f,0.f,0.f} : acc[MI][0],                 \
      0, 0, 0, 0x7F7F7F7F, 0, 0x7F7F7F7F);                                   \
  acc[MI][1] = __builtin_amdgcn_mfma_scale_f32_16x16x128_f8f6f4(             \
      AF, b1_, (CZ) ? (f32x4){0.f,0.f,0.f,0.f} : acc[MI][1],                 \
      0, 0, 0, 0x7F7F7F7F, 0, 0x7F7F7F7F);                                   \
  acc[MI][2] = __builtin_amdgcn_mfma_scale_f32_16x16x128_f8f6f4(             \
      AF, b2_, (CZ) ? (f32x4){0.f,0.f,0.f,0.f} : acc[MI][2],                 \
      0, 0, 0, 0x7F7F7F7F, 0, 0x7F7F7F7F);                                   \
  acc[MI][3] = __builtin_amdgcn_mfma_scale_f32_16x16x128_f8f6f4(             \
      AF, b3_, (CZ) ? (f32x4){0.f,0.f,0.f,0.f} : acc[MI][3],                 \
      0, 0, 0, 0x7F7F7F7F, 0, 0x7F7F7F7F);                                   \
  __builtin_amdgcn_s_setprio(0);                                             \
  __builtin_amdgcn_sched_barrier(0);

  // one K-half: 4 B-frags held; A-frags in a named 2-reg rotation (rule 20).
#define COMPUTE(P, KH, CZ) {                                                 \
    i32x8 b0_, b1_, b2_, b3_, a0_, a1_;                                      \
    READ_B8(b0_, 0, P) READ_B8(b1_, 1, P)                                    \
    READ_B8(b2_, 2, P) READ_B8(b3_, 3, P)                                    \
    READ_A8(a0_, 0, KH)                                                      \
    READ_A8(a1_, 1, KH)  MFMA4(a0_, 0, CZ)                                   \
    READ_A8(a0_, 2, KH)  MFMA4(a1_, 1, CZ)                                   \
    READ_A8(a1_, 3, KH)  MFMA4(a0_, 2, CZ)                                   \
    READ_A8(a0_, 4, KH)  MFMA4(a1_, 3, CZ)                                   \
    READ_A8(a1_, 5, KH)  MFMA4(a0_, 4, CZ)                                   \
    READ_A8(a0_, 6, KH)  MFMA4(a1_, 5, CZ)                                   \
    READ_A8(a1_, 7, KH)  MFMA4(a0_, 6, CZ)                                   \
    MFMA4(a1_, 7, CZ)                                                        \
    LGKM0();                                                                 \
  }

  // r13-verified epilogue (16x16 C/D layout; packed 4-value butterfly)
#define EPILOGUE(BN) {                                                        \
    _Pragma("unroll")                                                         \
    for (int mi = 0; mi < 8; ++mi)                                            \
      _Pragma("unroll")                                                       \
      for (int ni = 0; ni < 4; ++ni)                                          \
        _Pragma("unroll")                                                     \
        for (int r = 0; r < 4; ++r)                                           \
          acc[mi][ni][r] = __expf(acc[mi][ni][r] * INV_T);                    \
    bool sb0 = (lane & 1) != 0, sb1 = (lane & 2) != 0;                        \
    _Pragma("unroll")                                                         \
    for (int mi = 0; mi < 8; ++mi) {                                          \
      float v0 = acc[mi][0][0] + acc[mi][1][0] + acc[mi][2][0] + acc[mi][3][0]; \
      float v1 = acc[mi][0][1] + acc[mi][1][1] + acc[mi][2][1] + acc[mi][3][1]; \
      float v2 = acc[mi][0][2] + acc[mi][1][2] + acc[mi][2][2] + acc[mi][3][2]; \
      float v3 = acc[mi][0][3] + acc[mi][1][3] + acc[mi][2][3] + acc[mi][3][3]; \
      float h0 = (sb0 ? v1 : v0) + __shfl_xor(sb0 ? v0 : v1, 1);              \
      float h1 = (sb0 ? v3 : v2) + __shfl_xor(sb0 ? v2 : v3, 1);              \
      float g  = (sb1 ? h1 : h0) + __shfl_xor(sb1 ? h0 : h1, 2);              \
      g += __shfl_xor(g, 4);                                                  \
      g += __shfl_xor(g, 8);                                                  \
      if ((lane & 12) == 0)                                                   \
        rowpart[(size_t)((BN) * 4 + wn) * N + bm * 256 + wm * 128 + mi * 16 + \
                (lane >> 4) * 4 + (lane & 3)] = g;                            \
    }                                                                         \
    _Pragma("unroll")                                                         \
    for (int ni = 0; ni < 4; ++ni) {                                          \
      float v = 0.f;                                                          \
      _Pragma("unroll")                                                       \
      for (int mi = 0; mi < 8; ++mi)                                          \
        _Pragma("unroll")                                                     \
        for (int r = 0; r < 4; ++r)                                           \
          v += acc[mi][ni][r];                                                \
      v += __shfl_xor(v, 16); v += __shfl_xor(v, 32);                         \
      if (lane < 16)                                                          \
        colpart[(size_t)(bm * 2 + wm) * N + (BN) * 256 + wn * 64 + ni * 16 +  \
                lane] = v;                                                    \
    }                                                                         \
  }

#define TILE(j) (grp * 4 + (j))

  // ---- Prologue: A (8 loads/thread) + B(tile0, half0, half1)
  #pragma unroll
  for (int q = 0; q < 8; ++q) {
    int s = q * 512 + sb;
    int sub = s >> 10, row = (s >> 2) & 255;
    int u = (s & 3) ^ (((row >> 1) + (row >> 3)) & 3);
    __builtin_amdgcn_global_load_lds(
        (as1_void*)(A + (size_t)bm * 65536 + row * 256 + sub * 64 + u * 16),
        (as3_void*)(&AsF[q * 8192 + wv * 1024]), 16, 0, 0);
  }
  STAGE_B(0, TILE(0), 0)
  STAGE_B(1, TILE(0), 1)
  VMWAIT(4); BARRIER();   // A + half0 resident; half1 (newest 4) in flight

  // 8 half-steps; stage half i+2 into buf i&1 after the barrier frees it.
  COMPUTE(0, 0, 1) BARRIER();               STAGE_B(0, TILE(1), 0) VMWAIT(4); BARRIER();
  COMPUTE(1, 1, 0) BARRIER(); EPILOGUE(TILE(0)) STAGE_B(1, TILE(1), 1) VMWAIT(4); BARRIER();
  COMPUTE(0, 0, 1) BARRIER();               STAGE_B(0, TILE(2), 0) VMWAIT(4); BARRIER();
  COMPUTE(1, 1, 0) BARRIER(); EPILOGUE(TILE(1)) STAGE_B(1, TILE(2), 1) VMWAIT(4); BARRIER();
  COMPUTE(0, 0, 1) BARRIER();               STAGE_B(0, TILE(3), 0) VMWAIT(4); BARRIER();
  COMPUTE(1, 1, 0) BARRIER(); EPILOGUE(TILE(2)) STAGE_B(1, TILE(3), 1) VMWAIT(4); BARRIER();
  COMPUTE(0, 0, 1) BARRIER();               VMWAIT(0); BARRIER();
  COMPUTE(1, 1, 0) EPILOGUE(TILE(3))
  VMWAIT(0);  // retire final stores

#undef TILE
#undef EPILOGUE
#undef COMPUTE
#undef MFMA4
#undef READ_B8
#undef READ_A8
#undef STAGE_B
#undef VMWAIT
#undef LGKM0
#undef BARRIER
}

// Kernel 3: partial reduction + per-sample loss + atomic accumulate into out.
__global__ __launch_bounds__(256) void reduce_kernel(
    const float* __restrict__ rowpart, const float* __restrict__ colpart,
    const float* __restrict__ diag, float* __restrict__ out,
    int N, int NPr, int NPc) {
  __shared__ float redr[4][64], redc[4][64];
  int w = threadIdx.x >> 6, s = threadIdx.x & 63;
  int i = blockIdx.x * 64 + s;
  float rs = 0.f, cs = 0.f;
  for (int k = w; k < NPr; k += 4) rs += rowpart[(size_t)k * N + i];
  for (int k = w; k < NPc; k += 4) cs += colpart[(size_t)k * N + i];
  redr[w][s] = rs; redc[w][s] = cs;
  __syncthreads();
  if (w == 0) {
    float R = redr[0][s] + redr[1][s] + redr[2][s] + redr[3][s];
    float C = redc[0][s] + redc[1][s] + redc[2][s] + redc[3][s];
    float l = logf(R) + logf(C) - 2.0f * diag[i];
    #pragma unroll
    for (int m = 1; m < 64; m <<= 1) l += __shfl_xor(l, m);
    if (s == 0) atomicAdd(out, l * (0.5f / (float)N));
  }
}

extern "C" void kernel_launch(void* const* d_in, const int* in_sizes, int n_in,
                              void* d_out, int out_size, void* d_ws, size_t ws_size,
                              hipStream_t stream) {
  const float* images = (const float*)d_in[0];
  const float* captions = (const float*)d_in[1];
  int N = in_sizes[0] / D;   // 8192
  int NPr = 128;             // 32 bn-tiles x 4 wn
  int NPc = 64;              // 32 bm-blocks x 2 wm
  char* w = (char*)d_ws;
  size_t off = 0;
  unsigned char* imn  = (unsigned char*)(w + off); off += (size_t)N * D;
  unsigned char* capn = (unsigned char*)(w + off); off += (size_t)N * D;
  float* diag    = (float*)(w + off); off += (size_t)N * 4;
  float* rowpart = (float*)(w + off); off += (size_t)NPr * N * 4;
  float* colpart = (float*)(w + off); off += (size_t)NPc * N * 4;
  float* out = (float*)d_out;

  normalize_kernel<<<N / 4, 256, 0, stream>>>(images, captions, imn, capn, diag, N);
  gemm_exp_kernel<<<256, 512, 0, stream>>>(imn, capn, rowpart, colpart, N);
  hipMemsetAsync(out, 0, sizeof(float), stream);
  reduce_kernel<<<N / 64, 256, 0, stream>>>(rowpart, colpart, diag, out, N, NPr, NPc);
}